// Round 1
// baseline (661.842 us; speedup 1.0000x reference)
//
#include <hip/hip_runtime.h>
#include <hip/hip_bf16.h>
#include <math.h>

typedef __bf16 bf16_t;
typedef bf16_t bf16x8 __attribute__((ext_vector_type(8)));
typedef float f32x4 __attribute__((ext_vector_type(4)));

#define BB 4
#define SS 2048
#define HH 16
#define DMODEL 1024
#define DHEAD 64
#define LDA 40   // padded LDS row stride for 32-wide K tiles (80B, 16B-multiple)

__device__ inline unsigned short f2bf(float f) {
    union { __hip_bfloat16 h; unsigned short u; } cvt;
    cvt.h = __float2bfloat16(f);
    return cvt.u;
}

// ---------------- pack kernels ----------------

__global__ void pack_x(const float* __restrict__ x, unsigned short* __restrict__ xb) {
    int i = blockIdx.x * 256 + threadIdx.x;          // i indexes groups of 4
    const float4 v = ((const float4*)x)[i];
    unsigned short o[4] = { f2bf(v.x), f2bf(v.y), f2bf(v.z), f2bf(v.w) };
    *(uint2*)(xb + 4 * (size_t)i) = *(uint2*)o;
}

// WqkvT[n][k], n = mat*1024 + h*64 + d, k = m.  W_* is [H][DM][DH].
__global__ void pack_wqkv(const float* __restrict__ wq, const float* __restrict__ wk,
                          const float* __restrict__ wv, unsigned short* __restrict__ out) {
    int idx = blockIdx.x * 256 + threadIdx.x;        // 0..3072*1024-1
    int k  = idx & 1023;
    int n  = idx >> 10;
    int mat = n >> 10;
    int n1 = n & 1023;
    int h = n1 >> 6, d = n1 & 63;
    const float* w = (mat == 0) ? wq : (mat == 1) ? wk : wv;
    out[idx] = f2bf(w[(h << 16) + (k << 6) + d]);    // h*65536 + k*64 + d
}

// WoT[n][k], n = m_model, k = h*64+dh.  W_O is [H][DH][DM] = row-major [k][n].
__global__ void pack_wo(const float* __restrict__ wo, unsigned short* __restrict__ out) {
    int idx = blockIdx.x * 256 + threadIdx.x;        // 0..1024*1024-1
    int k = idx & 1023, n = idx >> 10;
    out[idx] = f2bf(wo[(k << 10) + n]);
}

// ---------------- GEMM 1: qkv = x @ WqkvT^T (+bias), scatter to [B,H,S,64] bf16 ----------------

__global__ __launch_bounds__(256) void gemm_qkv(
    const unsigned short* __restrict__ xb,    // [8192][1024] bf16
    const unsigned short* __restrict__ wT,    // [3072][1024] bf16 (N-major)
    const float* __restrict__ bq, const float* __restrict__ bk, const float* __restrict__ bv,
    unsigned short* __restrict__ qws, unsigned short* __restrict__ kws, unsigned short* __restrict__ vws)
{
    __shared__ __align__(16) unsigned short lA[64 * LDA];
    __shared__ __align__(16) unsigned short lB[64 * LDA];
    const int t = threadIdx.x;
    const int lane = t & 63;
    const int w = t >> 6;
    const int quad = lane >> 4;
    const int l15 = lane & 15;
    const int n0 = blockIdx.x * 64;
    const int m0 = blockIdx.y * 64;
    const int wm = (w >> 1) * 32;
    const int wn = (w & 1) * 32;

    f32x4 acc[2][2] = {};

    const int ar = t >> 2;
    const int ac = (t & 3) * 8;
    const unsigned short* Ag = xb + (size_t)(m0 + ar) * 1024 + ac;
    const unsigned short* Bg = wT + (size_t)(n0 + ar) * 1024 + ac;
    unsigned short* lAs = lA + ar * LDA + ac;
    unsigned short* lBs = lB + ar * LDA + ac;

    for (int kt = 0; kt < 1024; kt += 32) {
        __syncthreads();
        *(uint4*)lAs = *(const uint4*)(Ag + kt);
        *(uint4*)lBs = *(const uint4*)(Bg + kt);
        __syncthreads();
        bf16x8 af[2], bfr[2];
#pragma unroll
        for (int i = 0; i < 2; i++) {
            af[i]  = *(const bf16x8*)(lA + (wm + i * 16 + l15) * LDA + quad * 8);
            bfr[i] = *(const bf16x8*)(lB + (wn + i * 16 + l15) * LDA + quad * 8);
        }
#pragma unroll
        for (int i = 0; i < 2; i++)
#pragma unroll
            for (int j = 0; j < 2; j++)
                acc[i][j] = __builtin_amdgcn_mfma_f32_16x16x32_bf16(af[i], bfr[j], acc[i][j], 0, 0, 0);
    }

    // epilogue: D row = quad*4+r, col = lane&15
#pragma unroll
    for (int i = 0; i < 2; i++) {
        const int mbase = m0 + wm + i * 16 + quad * 4;
#pragma unroll
        for (int j = 0; j < 2; j++) {
            const int n = n0 + wn + j * 16 + l15;
            const int mat = n >> 10;
            const int n1 = n & 1023;
            const int h = n1 >> 6, d = n1 & 63;
            const float bias = (mat == 0 ? bq : mat == 1 ? bk : bv)[h * 64 + d];
            unsigned short* dst = (mat == 0 ? qws : mat == 1 ? kws : vws);
#pragma unroll
            for (int r = 0; r < 4; r++) {
                const int mm = mbase + r;
                const int b = mm >> 11, s = mm & 2047;
                dst[(size_t)((b * 16 + h) * 2048 + s) * 64 + d] = f2bf(acc[i][j][r] + bias);
            }
        }
    }
}

// ---------------- flash attention: per (b,h, 64-row q tile) ----------------

__global__ __launch_bounds__(256) void attn(
    const unsigned short* __restrict__ qws,
    const unsigned short* __restrict__ kws,
    const unsigned short* __restrict__ vws,
    unsigned short* __restrict__ zb)          // [8192][1024] bf16, col = h*64+d
{
    __shared__ __align__(16) unsigned short Qs[64 * 72];
    __shared__ __align__(16) unsigned short Ks[32 * 72];
    __shared__ __align__(16) unsigned short Vt[64 * LDA];       // transposed: [d][kpos]
    __shared__ __align__(16) unsigned short Ps[4 * 16 * LDA];   // per-wave P buffer

    const int t = threadIdx.x;
    const int lane = t & 63;
    const int w = t >> 6;
    const int quad = lane >> 4;
    const int l15 = lane & 15;

    const int qt = blockIdx.x & 31;
    const int bh = blockIdx.x >> 5;
    const int q0 = qt * 64;
    const size_t base = (size_t)bh * SS * DHEAD;
    const unsigned short* Q = qws + base;
    const unsigned short* K = kws + base;
    const unsigned short* V = vws + base;

    // stage Q tile [64][64] -> Qs [64][72]
    {
        const int r = t >> 2, c = (t & 3) * 8;
        *(uint4*)(Qs + r * 72 + c)      = *(const uint4*)(Q + (size_t)(q0 + r) * 64 + c);
        *(uint4*)(Qs + r * 72 + c + 32) = *(const uint4*)(Q + (size_t)(q0 + r) * 64 + c + 32);
    }
    __syncthreads();
    bf16x8 qf[2];
    qf[0] = *(const bf16x8*)(Qs + (w * 16 + l15) * 72 + quad * 8);
    qf[1] = *(const bf16x8*)(Qs + (w * 16 + l15) * 72 + quad * 8 + 32);

    f32x4 o[4] = {};
    float mst[4], lst[4];
#pragma unroll
    for (int r = 0; r < 4; r++) { mst[r] = -1e30f; lst[r] = 0.f; }

    const int nchunks = q0 / 32 + 2;    // kpos chunks of 32 up to diagonal
    unsigned short* Pw = Ps + w * 16 * LDA;

    for (int c = 0; c < nchunks; c++) {
        const int kb = c * 32;
        __syncthreads();   // prev readers of Ks/Vt done
        {
            const int r = t >> 3, cc = (t & 7) * 8;
            *(uint4*)(Ks + r * 72 + cc) = *(const uint4*)(K + (size_t)(kb + r) * 64 + cc);
            unsigned short tmp[8];
            *(uint4*)tmp = *(const uint4*)(V + (size_t)(kb + r) * 64 + cc);
#pragma unroll
            for (int i = 0; i < 8; i++) Vt[(cc + i) * LDA + r] = tmp[i];
        }
        __syncthreads();

        // scores: two 16-col subtiles
        float p[2][4];
        f32x4 sc[2];
#pragma unroll
        for (int sub = 0; sub < 2; sub++) {
            bf16x8 kf0 = *(const bf16x8*)(Ks + (sub * 16 + l15) * 72 + quad * 8);
            bf16x8 kf1 = *(const bf16x8*)(Ks + (sub * 16 + l15) * 72 + quad * 8 + 32);
            f32x4 s = {};
            s = __builtin_amdgcn_mfma_f32_16x16x32_bf16(qf[0], kf0, s, 0, 0, 0);
            s = __builtin_amdgcn_mfma_f32_16x16x32_bf16(qf[1], kf1, s, 0, 0, 0);
            const int kpos = kb + sub * 16 + l15;
#pragma unroll
            for (int r = 0; r < 4; r++) {
                const int qg = q0 + w * 16 + quad * 4 + r;
                float v = s[r] * 0.125f;
                if (kpos > qg) v = -1e30f;
                sc[sub][r] = v;
            }
        }
        // online softmax
#pragma unroll
        for (int r = 0; r < 4; r++) {
            float v = fmaxf(sc[0][r], sc[1][r]);
            v = fmaxf(v, __shfl_xor(v, 1));
            v = fmaxf(v, __shfl_xor(v, 2));
            v = fmaxf(v, __shfl_xor(v, 4));
            v = fmaxf(v, __shfl_xor(v, 8));
            float mnew = fmaxf(mst[r], v);
            float alpha = __expf(mst[r] - mnew);
            mst[r] = mnew;
            float p0 = __expf(sc[0][r] - mnew);
            float p1 = __expf(sc[1][r] - mnew);
            p[0][r] = p0; p[1][r] = p1;
            float rs = p0 + p1;
            rs += __shfl_xor(rs, 1);
            rs += __shfl_xor(rs, 2);
            rs += __shfl_xor(rs, 4);
            rs += __shfl_xor(rs, 8);
            lst[r] = alpha * lst[r] + rs;
            o[0][r] *= alpha; o[1][r] *= alpha; o[2][r] *= alpha; o[3][r] *= alpha;
        }
        // P (D-layout) -> LDS -> A-layout
#pragma unroll
        for (int sub = 0; sub < 2; sub++)
#pragma unroll
            for (int r = 0; r < 4; r++)
                Pw[(quad * 4 + r) * LDA + sub * 16 + l15] = f2bf(p[sub][r]);
        __syncthreads();
        bf16x8 pf = *(const bf16x8*)(Pw + l15 * LDA + quad * 8);
#pragma unroll
        for (int dt = 0; dt < 4; dt++) {
            bf16x8 vf = *(const bf16x8*)(Vt + (dt * 16 + l15) * LDA + quad * 8);
            o[dt] = __builtin_amdgcn_mfma_f32_16x16x32_bf16(pf, vf, o[dt], 0, 0, 0);
        }
    }

    // epilogue: z[(b*2048+q)*1024 + h*64 + d]
    const int b = bh >> 4, h = bh & 15;
    float inv[4];
#pragma unroll
    for (int r = 0; r < 4; r++) inv[r] = 1.0f / lst[r];
#pragma unroll
    for (int dt = 0; dt < 4; dt++) {
        const int d = dt * 16 + l15;
#pragma unroll
        for (int r = 0; r < 4; r++) {
            const int qg = q0 + w * 16 + quad * 4 + r;
            zb[(size_t)(b * 2048 + qg) * 1024 + h * 64 + d] = f2bf(o[dt][r] * inv[r]);
        }
    }
}

// ---------------- GEMM 2: out = z @ WoT^T + bO (fp32 out) ----------------

__global__ __launch_bounds__(256) void gemm_out(
    const unsigned short* __restrict__ zb,    // [8192][1024] bf16
    const unsigned short* __restrict__ wT,    // [1024][1024] bf16 (N-major)
    const float* __restrict__ bo,
    float* __restrict__ out)
{
    __shared__ __align__(16) unsigned short lA[64 * LDA];
    __shared__ __align__(16) unsigned short lB[64 * LDA];
    const int t = threadIdx.x;
    const int lane = t & 63;
    const int w = t >> 6;
    const int quad = lane >> 4;
    const int l15 = lane & 15;
    const int n0 = blockIdx.x * 64;
    const int m0 = blockIdx.y * 64;
    const int wm = (w >> 1) * 32;
    const int wn = (w & 1) * 32;

    f32x4 acc[2][2] = {};

    const int ar = t >> 2;
    const int ac = (t & 3) * 8;
    const unsigned short* Ag = zb + (size_t)(m0 + ar) * 1024 + ac;
    const unsigned short* Bg = wT + (size_t)(n0 + ar) * 1024 + ac;
    unsigned short* lAs = lA + ar * LDA + ac;
    unsigned short* lBs = lB + ar * LDA + ac;

    for (int kt = 0; kt < 1024; kt += 32) {
        __syncthreads();
        *(uint4*)lAs = *(const uint4*)(Ag + kt);
        *(uint4*)lBs = *(const uint4*)(Bg + kt);
        __syncthreads();
        bf16x8 af[2], bfr[2];
#pragma unroll
        for (int i = 0; i < 2; i++) {
            af[i]  = *(const bf16x8*)(lA + (wm + i * 16 + l15) * LDA + quad * 8);
            bfr[i] = *(const bf16x8*)(lB + (wn + i * 16 + l15) * LDA + quad * 8);
        }
#pragma unroll
        for (int i = 0; i < 2; i++)
#pragma unroll
            for (int j = 0; j < 2; j++)
                acc[i][j] = __builtin_amdgcn_mfma_f32_16x16x32_bf16(af[i], bfr[j], acc[i][j], 0, 0, 0);
    }

#pragma unroll
    for (int i = 0; i < 2; i++) {
        const int mbase = m0 + wm + i * 16 + quad * 4;
#pragma unroll
        for (int j = 0; j < 2; j++) {
            const int n = n0 + wn + j * 16 + l15;
            const float bias = bo[n];
#pragma unroll
            for (int r = 0; r < 4; r++)
                out[(size_t)(mbase + r) * 1024 + n] = acc[i][j][r] + bias;
        }
    }
}

// ---------------- launch ----------------

extern "C" void kernel_launch(void* const* d_in, const int* in_sizes, int n_in,
                              void* d_out, int out_size, void* d_ws, size_t ws_size,
                              hipStream_t stream) {
    const float* x  = (const float*)d_in[0];
    const float* WQ = (const float*)d_in[1];
    const float* WK = (const float*)d_in[2];
    const float* WV = (const float*)d_in[3];
    const float* WO = (const float*)d_in[4];
    const float* bQ = (const float*)d_in[5];
    const float* bK = (const float*)d_in[6];
    const float* bV = (const float*)d_in[7];
    const float* bO = (const float*)d_in[8];
    float* out = (float*)d_out;

    char* ws = (char*)d_ws;
    unsigned short* xb   = (unsigned short*)ws;                   // 16 MB (reused as z after gemm_qkv)
    unsigned short* wqkv = (unsigned short*)(ws + (16u << 20));   // 6 MB
    unsigned short* woT  = (unsigned short*)(ws + (22u << 20));   // 2 MB
    unsigned short* qws  = (unsigned short*)(ws + (24u << 20));   // 16 MB
    unsigned short* kws  = (unsigned short*)(ws + (40u << 20));   // 16 MB
    unsigned short* vws  = (unsigned short*)(ws + (56u << 20));   // 16 MB
    unsigned short* zbuf = xb;                                    // reuse: x dead after gemm_qkv

    pack_x<<<8192, 256, 0, stream>>>(x, xb);                                  // 8M elems / 4 per thread
    pack_wqkv<<<(3072 * 1024) / 256, 256, 0, stream>>>(WQ, WK, WV, wqkv);
    pack_wo<<<(1024 * 1024) / 256, 256, 0, stream>>>(WO, woT);
    gemm_qkv<<<dim3(48, 128), 256, 0, stream>>>(xb, wqkv, bQ, bK, bV, qws, kws, vws);
    attn<<<2048, 256, 0, stream>>>(qws, kws, vws, zbuf);
    gemm_out<<<dim3(16, 128), 256, 0, stream>>>(zbuf, woT, bO, out);
}